// Round 8
// baseline (142.716 us; speedup 1.0000x reference)
//
#include <hip/hip_runtime.h>

#define NT 256
#define NB 1024    // persistent: 4 blocks/CU, 16 waves/CU at min-waves/EU=4
#define ITERS 4    // NB*NT*ITERS = 1048576 = B/4 quads exactly

// All role constants are compile-time literals (R6: cut VALU work ~20%).
// wmid chain (continuous): ramp [0,a), 1 [a,b], down (b,c), 0 [c,d], tail >d.
// tail = -1 + 2^(1 - t/d) (k = ln2/d). down = 1-(t-b)/(c-b) folded into fma.

__device__ __forceinline__ float loss_head(float p, float t) {
    int ap = (p>=150.0f)+(p>=500.0f)+(p>=1000.0f)+(p>=1800.0f)+(p>=2600.0f);
    int at = (t>=150.0f)+(t>=500.0f)+(t>=1000.0f)+(t>=1800.0f)+(t>=2600.0f);
    float wc = exp2f(fabsf((float)(ap-at)) * 0.13750352374993502f); // 1.1^|d|
    float wm = fmaxf(fminf(fminf(t*0.0125f, 1.0f), fmaf(t,-0.004f,7.0f)), 0.0f);
    float tail = exp2f(fmaf(t,-0.0005f,1.0f)) - 1.0f;
    wm = (t>2000.0f) ? tail : wm;
    wm += (p<0.0f) ? 2.0f : 1.0f;
    return fabsf(p-t)*wc*wm;
}

// AIS compare in scaled space: p*rs >= thr  <=>  p >= thr*s (rs = 1/s, v_rcp).
// wmid uses RAW t (reference scales only the AIS thresholds).
__device__ __forceinline__ float loss_chest(float p, float t, float rs) {
    float ps = p*rs, ts = t*rs;
    int ap = (ps>=22.0f)+(ps>=35.0f)+(ps>=45.0f)+(ps>=55.0f)+(ps>=65.0f);
    int at = (ts>=22.0f)+(ts>=35.0f)+(ts>=45.0f)+(ts>=55.0f)+(ts>=65.0f);
    float wc = exp2f(fabsf((float)(ap-at)) * 0.13750352374993502f);
    float wm = fmaxf(fminf(fminf(t*0.1f, 1.0f), fmaf(t,-0.1f,8.5f)), 0.0f);
    float tail = exp2f(fmaf(t,-0.01f,1.0f)) - 1.0f;
    wm = (t>100.0f) ? tail : wm;
    wm += (p<0.0f) ? 2.0f : 1.0f;
    return fabsf(p-t)*wc*wm;
}

__device__ __forceinline__ float loss_neck(float p, float t) {
    int ap = (p>=0.2f)+(p>=0.5f)+(p>=1.0f)+(p>=1.5f)+(p>=2.0f);
    int at = (t>=0.2f)+(t>=0.5f)+(t>=1.0f)+(t>=1.5f)+(t>=2.0f);
    float wc = exp2f(fabsf((float)(ap-at)) * 0.13750352374993502f);
    float wm = fmaxf(fminf(fminf(t*6.6666667f, 1.0f), fmaf(t,-5.0f,8.5f)), 0.0f);
    float tail = exp2f(fmaf(t,-0.52631579f,1.0f)) - 1.0f;
    wm = (t>1.9f) ? tail : wm;
    wm += (p<0.0f) ? 2.0f : 1.0f;
    return fabsf(p-t)*wc*wm;
}

// 4 rows = 3 float4 of pred/true + 1 int4 of ot. Fixed slot roles:
// p0=(h,d,n,h) p1=(d,n,h,d) p2=(n,h,d,n)
__device__ __forceinline__ float quad_loss(float4 p0, float4 p1, float4 p2,
                                           float4 t0, float4 t1, float4 t2,
                                           int4 o) {
    float r0 = __builtin_amdgcn_rcpf(fmaf(0.1f,(float)o.x,0.8f));
    float r1 = __builtin_amdgcn_rcpf(fmaf(0.1f,(float)o.y,0.8f));
    float r2 = __builtin_amdgcn_rcpf(fmaf(0.1f,(float)o.z,0.8f));
    float r3 = __builtin_amdgcn_rcpf(fmaf(0.1f,(float)o.w,0.8f));
    float a;
    a  = loss_head (p0.x,t0.x) + loss_chest(p0.y,t0.y,r0) + loss_neck(p0.z,t0.z);
    a += loss_head (p0.w,t0.w) + loss_chest(p1.x,t1.x,r1) + loss_neck(p1.y,t1.y);
    a += loss_head (p1.z,t1.z) + loss_chest(p1.w,t1.w,r2) + loss_neck(p2.x,t2.x);
    a += loss_head (p2.y,t2.y) + loss_chest(p2.z,t2.z,r3) + loss_neck(p2.w,t2.w);
    return a;
}

// Persistent 2-stage register pipeline: prefetch quad k+1's 7 loads while
// computing quad k. __launch_bounds__(NT,4) grants a 128-VGPR budget so the
// scheduler has no occupancy-pressure reason to re-sink the prefetch (the
// R5/R6 failure mode: VGPR pinned at 32-36, loads sunk to use sites).
__global__ __launch_bounds__(NT, 4)
void weighted_loss_main(const float* __restrict__ pred,
                        const float* __restrict__ truth,
                        const int*   __restrict__ ot,
                        float* __restrict__ partial, int B) {
    const int nquad = B >> 2;
    const int g = blockIdx.x * NT + threadIdx.x;
    const int T = gridDim.x * NT;
    const float4* p4 = (const float4*)pred;
    const float4* t4 = (const float4*)truth;
    const int4*   o4 = (const int4*)ot;

    float acc = 0.0f;

    if (nquad == T * ITERS) {
        // ---- software pipeline, trip count known at compile time ----
        float4 P0, P1, P2, Q0, Q1, Q2;  int4 O;
        {
            const int q = g;
            P0 = p4[3*q]; P1 = p4[3*q+1]; P2 = p4[3*q+2];
            Q0 = t4[3*q]; Q1 = t4[3*q+1]; Q2 = t4[3*q+2];
            O  = o4[q];
        }
        #pragma unroll
        for (int k = 0; k < ITERS; ++k) {
            float4 nP0, nP1, nP2, nQ0, nQ1, nQ2;  int4 nO;
            if (k + 1 < ITERS) {               // static under unroll
                const int q = g + (k + 1) * T;
                nP0 = p4[3*q]; nP1 = p4[3*q+1]; nP2 = p4[3*q+2];
                nQ0 = t4[3*q]; nQ1 = t4[3*q+1]; nQ2 = t4[3*q+2];
                nO  = o4[q];
            }
            acc += quad_loss(P0, P1, P2, Q0, Q1, Q2, O);
            if (k + 1 < ITERS) {
                P0 = nP0; P1 = nP1; P2 = nP2;
                Q0 = nQ0; Q1 = nQ1; Q2 = nQ2;
                O  = nO;
            }
        }
    } else {
        // Generic fallback: grid-stride over quads + row tail.
        for (int q = g; q < nquad; q += T) {
            float4 p0=p4[3*q], p1=p4[3*q+1], p2=p4[3*q+2];
            float4 t0=t4[3*q], t1=t4[3*q+1], t2=t4[3*q+2];
            int4 o = o4[q];
            acc += quad_loss(p0,p1,p2, t0,t1,t2, o);
        }
        for (int r = (nquad<<2) + g; r < B; r += T) {
            float rs = __builtin_amdgcn_rcpf(fmaf(0.1f,(float)ot[r],0.8f));
            acc += loss_head (pred[3*r],   truth[3*r])
                 + loss_chest(pred[3*r+1], truth[3*r+1], rs)
                 + loss_neck (pred[3*r+2], truth[3*r+2]);
        }
    }

    // wave (64) reduce then cross-wave via LDS
    #pragma unroll
    for (int off = 32; off > 0; off >>= 1) acc += __shfl_down(acc, off, 64);
    __shared__ float sm[NT / 64];
    const int lane = threadIdx.x & 63, wid = threadIdx.x >> 6;
    if (lane == 0) sm[wid] = acc;
    __syncthreads();
    if (threadIdx.x == 0) {
        float s = 0.0f;
        #pragma unroll
        for (int w = 0; w < NT / 64; ++w) s += sm[w];
        partial[blockIdx.x] = s;
    }
}

__global__ __launch_bounds__(1024)
void weighted_loss_reduce(const float* __restrict__ partial, int n,
                          float* __restrict__ out, float invB) {
    float acc = 0.0f;
    for (int i = threadIdx.x; i < n; i += blockDim.x) acc += partial[i];
    #pragma unroll
    for (int off = 32; off > 0; off >>= 1) acc += __shfl_down(acc, off, 64);
    __shared__ float sm[16];
    const int lane = threadIdx.x & 63, wid = threadIdx.x >> 6;
    if (lane == 0) sm[wid] = acc;
    __syncthreads();
    if (threadIdx.x == 0) {
        float s = 0.0f;
        #pragma unroll
        for (int w = 0; w < 16; ++w) s += sm[w];
        out[0] = s * invB;
    }
}

extern "C" void kernel_launch(void* const* d_in, const int* in_sizes, int n_in,
                              void* d_out, int out_size, void* d_ws, size_t ws_size,
                              hipStream_t stream) {
    const float* pred  = (const float*)d_in[0];   // (B,3) f32
    const float* truth = (const float*)d_in[1];   // (B,3) f32
    const int*   ot    = (const int*)d_in[2];     // (B,)  i32
    const int B = in_sizes[2];
    float* partial = (float*)d_ws;                // NB floats, fully overwritten

    weighted_loss_main<<<NB, NT, 0, stream>>>(pred, truth, ot, partial, B);
    weighted_loss_reduce<<<1, 1024, 0, stream>>>(partial, NB, (float*)d_out,
                                                 1.0f / (float)B);
}

// Round 10
// 137.364 us; speedup vs baseline: 1.0390x; 1.0390x over previous
//
#include <hip/hip_runtime.h>

#define NT 256
#define NB 4096   // NB*NT = 1048576 = B/4 quads -> exactly 1 quad/thread

// Native clang vector types: __builtin_nontemporal_load needs pointer to
// scalar or vector-of-scalar (HIP_vector_type struct is rejected).
typedef float vf4 __attribute__((ext_vector_type(4)));
typedef int   vi4 __attribute__((ext_vector_type(4)));

// All role constants are compile-time literals (R6: cut VALU work ~20%).
// wmid chain (continuous): ramp [0,a), 1 [a,b], down (b,c), 0 [c,d], tail >d.
// tail = -1 + 2^(1 - t/d) (k = ln2/d). down = 1-(t-b)/(c-b) folded into fma.

__device__ __forceinline__ float loss_head(float p, float t) {
    int ap = (p>=150.0f)+(p>=500.0f)+(p>=1000.0f)+(p>=1800.0f)+(p>=2600.0f);
    int at = (t>=150.0f)+(t>=500.0f)+(t>=1000.0f)+(t>=1800.0f)+(t>=2600.0f);
    float wc = exp2f(fabsf((float)(ap-at)) * 0.13750352374993502f); // 1.1^|d|
    float wm = fmaxf(fminf(fminf(t*0.0125f, 1.0f), fmaf(t,-0.004f,7.0f)), 0.0f);
    float tail = exp2f(fmaf(t,-0.0005f,1.0f)) - 1.0f;
    wm = (t>2000.0f) ? tail : wm;
    wm += (p<0.0f) ? 2.0f : 1.0f;
    return fabsf(p-t)*wc*wm;
}

// AIS compare in scaled space: p*rs >= thr  <=>  p >= thr*s (rs = 1/s, v_rcp).
// wmid uses RAW t (reference scales only the AIS thresholds).
__device__ __forceinline__ float loss_chest(float p, float t, float rs) {
    float ps = p*rs, ts = t*rs;
    int ap = (ps>=22.0f)+(ps>=35.0f)+(ps>=45.0f)+(ps>=55.0f)+(ps>=65.0f);
    int at = (ts>=22.0f)+(ts>=35.0f)+(ts>=45.0f)+(ts>=55.0f)+(ts>=65.0f);
    float wc = exp2f(fabsf((float)(ap-at)) * 0.13750352374993502f);
    float wm = fmaxf(fminf(fminf(t*0.1f, 1.0f), fmaf(t,-0.1f,8.5f)), 0.0f);
    float tail = exp2f(fmaf(t,-0.01f,1.0f)) - 1.0f;
    wm = (t>100.0f) ? tail : wm;
    wm += (p<0.0f) ? 2.0f : 1.0f;
    return fabsf(p-t)*wc*wm;
}

__device__ __forceinline__ float loss_neck(float p, float t) {
    int ap = (p>=0.2f)+(p>=0.5f)+(p>=1.0f)+(p>=1.5f)+(p>=2.0f);
    int at = (t>=0.2f)+(t>=0.5f)+(t>=1.0f)+(t>=1.5f)+(t>=2.0f);
    float wc = exp2f(fabsf((float)(ap-at)) * 0.13750352374993502f);
    float wm = fmaxf(fminf(fminf(t*6.6666667f, 1.0f), fmaf(t,-5.0f,8.5f)), 0.0f);
    float tail = exp2f(fmaf(t,-0.52631579f,1.0f)) - 1.0f;
    wm = (t>1.9f) ? tail : wm;
    wm += (p<0.0f) ? 2.0f : 1.0f;
    return fabsf(p-t)*wc*wm;
}

// 4 rows = 3 vf4 of pred/true + 1 vi4 of ot. Fixed slot roles:
// p0=(h,d,n,h) p1=(d,n,h,d) p2=(n,h,d,n)
__device__ __forceinline__ float quad_loss(vf4 p0, vf4 p1, vf4 p2,
                                           vf4 t0, vf4 t1, vf4 t2,
                                           vi4 o) {
    float r0 = __builtin_amdgcn_rcpf(fmaf(0.1f,(float)o.x,0.8f));
    float r1 = __builtin_amdgcn_rcpf(fmaf(0.1f,(float)o.y,0.8f));
    float r2 = __builtin_amdgcn_rcpf(fmaf(0.1f,(float)o.z,0.8f));
    float r3 = __builtin_amdgcn_rcpf(fmaf(0.1f,(float)o.w,0.8f));
    float a;
    a  = loss_head (p0.x,t0.x) + loss_chest(p0.y,t0.y,r0) + loss_neck(p0.z,t0.z);
    a += loss_head (p0.w,t0.w) + loss_chest(p1.x,t1.x,r1) + loss_neck(p1.y,t1.y);
    a += loss_head (p1.z,t1.z) + loss_chest(p1.w,t1.w,r2) + loss_neck(p2.x,t2.x);
    a += loss_head (p2.y,t2.y) + loss_chest(p2.z,t2.z,r3) + loss_neck(p2.w,t2.w);
    return a;
}

// R7 structure (single rolling front, 1 quad/thread — best so far) with all
// big loads non-temporal: data is single-touch streaming, so bypass L1
// allocation (nt) — tests whether the ~4.6 B/cyc/CU read cap lives in the
// TCP/L1 miss-tracking path.
__global__ __launch_bounds__(NT)
void weighted_loss_main(const float* __restrict__ pred,
                        const float* __restrict__ truth,
                        const int*   __restrict__ ot,
                        float* __restrict__ partial, int B) {
    const int nquad = B >> 2;
    const int g = blockIdx.x * NT + threadIdx.x;
    const int T = gridDim.x * NT;
    const vf4* p4 = (const vf4*)pred;
    const vf4* t4 = (const vf4*)truth;
    const vi4* o4 = (const vi4*)ot;

    float acc = 0.0f;

    for (int q = g; q < nquad; q += T) {   // exactly 1 iter when T == nquad
        vf4 p0 = __builtin_nontemporal_load(&p4[3*q]);
        vf4 p1 = __builtin_nontemporal_load(&p4[3*q+1]);
        vf4 p2 = __builtin_nontemporal_load(&p4[3*q+2]);
        vf4 t0 = __builtin_nontemporal_load(&t4[3*q]);
        vf4 t1 = __builtin_nontemporal_load(&t4[3*q+1]);
        vf4 t2 = __builtin_nontemporal_load(&t4[3*q+2]);
        vi4 o  = __builtin_nontemporal_load(&o4[q]);
        acc += quad_loss(p0,p1,p2, t0,t1,t2, o);
    }
    // row tail (B not multiple of 4) — empty for B=4M
    for (int r = (nquad<<2) + g; r < B; r += T) {
        float rs = __builtin_amdgcn_rcpf(fmaf(0.1f,(float)ot[r],0.8f));
        acc += loss_head (pred[3*r],   truth[3*r])
             + loss_chest(pred[3*r+1], truth[3*r+1], rs)
             + loss_neck (pred[3*r+2], truth[3*r+2]);
    }

    // wave (64) reduce then cross-wave via LDS
    #pragma unroll
    for (int off = 32; off > 0; off >>= 1) acc += __shfl_down(acc, off, 64);
    __shared__ float sm[NT / 64];
    const int lane = threadIdx.x & 63, wid = threadIdx.x >> 6;
    if (lane == 0) sm[wid] = acc;
    __syncthreads();
    if (threadIdx.x == 0) {
        float s = 0.0f;
        #pragma unroll
        for (int w = 0; w < NT / 64; ++w) s += sm[w];
        partial[blockIdx.x] = s;
    }
}

__global__ __launch_bounds__(1024)
void weighted_loss_reduce(const float* __restrict__ partial, int n,
                          float* __restrict__ out, float invB) {
    float acc = 0.0f;
    for (int i = threadIdx.x; i < n; i += blockDim.x) acc += partial[i];
    #pragma unroll
    for (int off = 32; off > 0; off >>= 1) acc += __shfl_down(acc, off, 64);
    __shared__ float sm[16];
    const int lane = threadIdx.x & 63, wid = threadIdx.x >> 6;
    if (lane == 0) sm[wid] = acc;
    __syncthreads();
    if (threadIdx.x == 0) {
        float s = 0.0f;
        #pragma unroll
        for (int w = 0; w < 16; ++w) s += sm[w];
        out[0] = s * invB;
    }
}

extern "C" void kernel_launch(void* const* d_in, const int* in_sizes, int n_in,
                              void* d_out, int out_size, void* d_ws, size_t ws_size,
                              hipStream_t stream) {
    const float* pred  = (const float*)d_in[0];   // (B,3) f32
    const float* truth = (const float*)d_in[1];   // (B,3) f32
    const int*   ot    = (const int*)d_in[2];     // (B,)  i32
    const int B = in_sizes[2];
    float* partial = (float*)d_ws;                // NB floats, fully overwritten

    weighted_loss_main<<<NB, NT, 0, stream>>>(pred, truth, ot, partial, B);
    weighted_loss_reduce<<<1, 1024, 0, stream>>>(partial, NB, (float*)d_out,
                                                 1.0f / (float)B);
}